// Round 1
// baseline (277.502 us; speedup 1.0000x reference)
//
#include <hip/hip_runtime.h>
#include <math.h>

#define T_TOK 65536
#define K_CODE 1024
#define E_DIM 64
#define DECAYF 0.99f
#define EPSF 1e-5f

#define XREG 44           // x[0..43] in VGPRs
#define XLDS (64 - XREG)  // x[44..63] in per-wave LDS
#define NWAVE 8           // waves per block (each owns 64 tokens)
#define NSEG 8            // code segments; seg = blockIdx & 7 -> XCD-affine
#define SEG_K (K_CODE / NSEG)  // 128 codes per segment

// --- exact-rounding helpers: block ffp-contract=fast fusion ---
__device__ __forceinline__ float mul_nf(float a, float b) {
#pragma clang fp contract(off)
    return a * b;
}
__device__ __forceinline__ float add_nf(float a, float b) {
#pragma clang fp contract(off)
    return a + b;
}
__device__ __forceinline__ float sub_nf(float a, float b) {
#pragma clang fp contract(off)
    return a - b;
}

// numpy pairwise_sum for n=64 of elementwise squares
__device__ __forceinline__ float np_sq_sum64(const float* v) {
    float r[8];
#pragma unroll
    for (int j = 0; j < 8; ++j) r[j] = mul_nf(v[j], v[j]);
#pragma unroll
    for (int i = 8; i < 64; i += 8) {
#pragma unroll
        for (int j = 0; j < 8; ++j) r[j] = add_nf(r[j], mul_nf(v[i + j], v[i + j]));
    }
    float s01 = add_nf(r[0], r[1]);
    float s23 = add_nf(r[2], r[3]);
    float s45 = add_nf(r[4], r[5]);
    float s67 = add_nf(r[6], r[7]);
    return add_nf(add_nf(s01, s23), add_nf(s45, s67));
}

// ws layout (floats):
// [0, 1024)                  wnorm
// [1024]                     diff accumulator
// [1025]                     n (sum of new_cluster_size)
// [2048, 2048+131072)        keys: u64[65536] argmin keys (memset 0xFF)
// [133120, 133120+8*1024)    onehot replicas
// [141312, 141312+nrep*65536) embed_sum replicas

__global__ __launch_bounds__(256) void wnorm_kernel(const float* __restrict__ embed,
                                                    float* __restrict__ wnorm) {
    int k = blockIdx.x * 256 + threadIdx.x;
    if (k < K_CODE) {
        float w[64];
        const float4* wp = reinterpret_cast<const float4*>(embed + (size_t)k * E_DIM);
#pragma unroll
        for (int i = 0; i < 16; ++i) {
            float4 v = wp[i];
            w[4 * i + 0] = v.x; w[4 * i + 1] = v.y; w[4 * i + 2] = v.z; w[4 * i + 3] = v.w;
        }
        wnorm[k] = np_sq_sum64(w);
    }
}

// Block = 512 threads = 8 waves; 512 tokens/block (wave owns 64 tokens),
// ALL waves scan the SAME 128-code segment seg = blockIdx & 7.
//  - scalar w-stream is 32 KB, shared by all 8 waves (and by the CU's
//    resident blocks + the XCD's blocks via bid%8 round-robin) -> the
//    per-batch lgkmcnt(0) SMEM drains hit K$/L2-warm lines instead of
//    thrashing 256 KB/CU as in the old per-wave-segment layout
//  - no __syncthreads anywhere: xl is per-wave private, waves de-phase
//  - per-(token,code) arithmetic bit-identical to the verified kernel
//    (sequential i=0..63 FMA chain, same dist rounding, ascending-k
//    strict-<); cross-segment combine via packed-u64 atomicMin whose key
//    (monotone_dist<<32)|idx reproduces np argmin first-min semantics
__global__ __launch_bounds__(512) void argmin_kernel(const float* __restrict__ z_e,
                                                     const float* __restrict__ embed,
                                                     const float* __restrict__ wnorm,
                                                     unsigned long long* __restrict__ keys) {
    __shared__ float xl[NWAVE][XLDS][64];  // 20 KB, per-wave private tail dims

    int lane = threadIdx.x & 63;
    int wave = threadIdx.x >> 6;
    int wu = __builtin_amdgcn_readfirstlane(wave);  // provably uniform
    int seg = blockIdx.x & (NSEG - 1);
    int tgrp = blockIdx.x >> 3;
    int t = tgrp * (NWAVE * 64) + wu * 64 + lane;

    // Load this wave's 64 tokens; accumulate numpy-exact ||x||^2 (strided-8
    // pairwise) exactly as the verified kernel did.
    const float4* xp = reinterpret_cast<const float4*>(z_e + (size_t)t * E_DIM);
    float xr[XREG];
    float r[8];
#pragma unroll
    for (int g = 0; g < 8; ++g) {
        float4 va = xp[2 * g], vb = xp[2 * g + 1];
        float e[8] = {va.x, va.y, va.z, va.w, vb.x, vb.y, vb.z, vb.w};
#pragma unroll
        for (int j = 0; j < 8; ++j) {
            int i = 8 * g + j;
            if (g == 0) r[j] = mul_nf(e[j], e[j]);
            else        r[j] = add_nf(r[j], mul_nf(e[j], e[j]));
            if (i < XREG) xr[i] = e[j];
            else xl[wu][i - XREG][lane] = e[j];  // same-wave write/read, no barrier
        }
    }
    float s01 = add_nf(r[0], r[1]);
    float s23 = add_nf(r[2], r[3]);
    float s45 = add_nf(r[4], r[5]);
    float s67 = add_nf(r[6], r[7]);
    float xn = add_nf(add_nf(s01, s23), add_nf(s45, s67));

    float best = INFINITY;
    int k0 = seg * SEG_K;
    int idx = k0;

    for (int k = k0; k < k0 + SEG_K; k += 4) {
        const float* wr = embed + (size_t)k * E_DIM;  // uniform -> s_load
        float d0 = 0.f, d1 = 0.f, d2 = 0.f, d3 = 0.f;
#pragma unroll
        for (int i = 0; i < XREG; ++i) {
            float xv = xr[i];
            d0 = __builtin_fmaf(xv, wr[i], d0);
            d1 = __builtin_fmaf(xv, wr[E_DIM + i], d1);
            d2 = __builtin_fmaf(xv, wr[2 * E_DIM + i], d2);
            d3 = __builtin_fmaf(xv, wr[3 * E_DIM + i], d3);
        }
#pragma unroll
        for (int j = 0; j < XLDS; ++j) {
            float xv = xl[wu][j][lane];
            d0 = __builtin_fmaf(xv, wr[XREG + j], d0);
            d1 = __builtin_fmaf(xv, wr[E_DIM + XREG + j], d1);
            d2 = __builtin_fmaf(xv, wr[2 * E_DIM + XREG + j], d2);
            d3 = __builtin_fmaf(xv, wr[3 * E_DIM + XREG + j], d3);
        }
        float dist0 = add_nf(sub_nf(xn, d0 + d0), wnorm[k]);
        float dist1 = add_nf(sub_nf(xn, d1 + d1), wnorm[k + 1]);
        float dist2 = add_nf(sub_nf(xn, d2 + d2), wnorm[k + 2]);
        float dist3 = add_nf(sub_nf(xn, d3 + d3), wnorm[k + 3]);
        if (dist0 < best) { best = dist0; idx = k; }
        if (dist1 < best) { best = dist1; idx = k + 1; }
        if (dist2 < best) { best = dist2; idx = k + 2; }
        if (dist3 < best) { best = dist3; idx = k + 3; }
    }

    // monotone total-order map for finite floats (handles negatives too),
    // then lexicographic (dist, idx) -> u64 atomicMin == np first-min.
    unsigned int b = __float_as_uint(best);
    unsigned int mk = (b & 0x80000000u) ? ~b : (b | 0x80000000u);
    unsigned long long key = ((unsigned long long)mk << 32) | (unsigned int)idx;
    atomicMin(&keys[t], key);
}

// Combine: gather winner, straight-through z_q + diff partial, fused EMA
// scatter. Block = 256 threads handles 64 tokens. Scatter reads x with
// lane=dim DIRECTLY from z_e (contiguous 256B rows -> coalesced), so no
// transpose LDS is needed. Same np rounding (r = fl(w-x); out = fl(x+r));
// diff/esum accumulation order is atomic-nondeterministic exactly like the
// previously-passing kernel.
__global__ __launch_bounds__(256) void combine_kernel(const float* __restrict__ z_e,
                                                      const float* __restrict__ embed,
                                                      const unsigned long long* __restrict__ keys,
                                                      float* __restrict__ out_zq,
                                                      float* __restrict__ out_ind,
                                                      float* __restrict__ diff_acc,
                                                      float* __restrict__ esum_rep,
                                                      float* __restrict__ onehot_rep,
                                                      int rep_mask) {
    __shared__ int sidx[64];
    __shared__ float sred[4];
    int tid = threadIdx.x;
    int t0 = blockIdx.x * 64;

    if (tid < 64) {
        unsigned long long kv = keys[t0 + tid];
        int bi = (int)(kv & 0x3FFull);
        sidx[tid] = bi;
        out_ind[t0 + tid] = (float)bi;
    }
    __syncthreads();

    // z_q + diff: 1024 (token, float4-chunk) units over 256 threads
    float ds = 0.f;
#pragma unroll
    for (int u = 0; u < 4; ++u) {
        int v = u * 256 + tid;
        int tl = v >> 4;
        int c = v & 15;
        int bi = sidx[tl];
        float4 w4 = *reinterpret_cast<const float4*>(embed + (size_t)bi * E_DIM + c * 4);
        float4 x4 = *reinterpret_cast<const float4*>(z_e + (size_t)(t0 + tl) * E_DIM + c * 4);
        float rx = sub_nf(w4.x, x4.x);
        float ry = sub_nf(w4.y, x4.y);
        float rz = sub_nf(w4.z, x4.z);
        float rw = sub_nf(w4.w, x4.w);
        float4 o;
        o.x = add_nf(x4.x, rx);
        o.y = add_nf(x4.y, ry);
        o.z = add_nf(x4.z, rz);
        o.w = add_nf(x4.w, rw);
        *reinterpret_cast<float4*>(out_zq + (size_t)(t0 + tl) * E_DIM + c * 4) = o;
        ds = __builtin_fmaf(rx, rx, ds);
        ds = __builtin_fmaf(ry, ry, ds);
        ds = __builtin_fmaf(rz, rz, ds);
        ds = __builtin_fmaf(rw, rw, ds);
    }
#pragma unroll
    for (int o = 32; o > 0; o >>= 1) ds += __shfl_down(ds, o, 64);
    if ((tid & 63) == 0) sred[tid >> 6] = ds;
    __syncthreads();
    if (tid == 0) atomicAdd(diff_acc, sred[0] + sred[1] + sred[2] + sred[3]);

    // fused EMA scatter, lane = dim -> one coalesced 256B row-atomic per token
    int lane = tid & 63;
    int wv = tid >> 6;
    int rep = blockIdx.x & rep_mask;
    float* esum = esum_rep + (size_t)rep * (K_CODE * E_DIM);
    float* onehot = onehot_rep + (size_t)rep * K_CODE;
#pragma unroll
    for (int j = 0; j < 16; ++j) {
        int tl = wv * 16 + j;
        int bi = sidx[tl];
        float xv = z_e[(size_t)(t0 + tl) * E_DIM + lane];
        atomicAdd(&esum[(size_t)bi * E_DIM + lane], xv);
        if (lane == 0) atomicAdd(&onehot[bi], 1.0f);
    }
}

// ncs, n, diff: single block (tiny)
__global__ __launch_bounds__(1024) void finalize_cs_kernel(const float* __restrict__ cluster_size,
                                                           const float* __restrict__ onehot_rep,
                                                           const float* __restrict__ ws_diff,
                                                           float* __restrict__ out_diff,
                                                           float* __restrict__ out_ncs,
                                                           float* __restrict__ ws_n,
                                                           int nrep) {
    int k = threadIdx.x;
    float oh = 0.f;
    for (int r = 0; r < nrep; ++r) oh += onehot_rep[(size_t)r * K_CODE + k];
    float ncs = DECAYF * cluster_size[k] + (1.0f - DECAYF) * oh;
    out_ncs[k] = ncs;

    __shared__ float red[1024];
    red[k] = ncs;
    __syncthreads();
#pragma unroll
    for (int s = 512; s > 0; s >>= 1) {
        if (k < s) red[k] += red[k + s];
        __syncthreads();
    }
    if (k == 0) {
        ws_n[0] = red[0];
        out_diff[0] = ws_diff[0] * (1.0f / 4194304.0f);  // /2^22 exact
    }
}

// embed_avg / embed update spread across 64 blocks
__global__ __launch_bounds__(256) void finalize_embed_kernel(const float* __restrict__ embed_avg,
                                                             const float* __restrict__ esum_rep,
                                                             const float* __restrict__ out_ncs,
                                                             const float* __restrict__ ws_n,
                                                             float* __restrict__ out_ne,
                                                             float* __restrict__ out_nea,
                                                             int nrep) {
    int gid = blockIdx.x * 256 + threadIdx.x;
    int k = gid >> 4;        // row
    int c = gid & 15;        // float4 chunk
    float n = ws_n[0];
    float ncs = out_ncs[k];
    float cs = (ncs + EPSF) / (n + (float)K_CODE * EPSF) * n;

    size_t off = (size_t)k * E_DIM + (size_t)c * 4;
    float4 s4 = make_float4(0.f, 0.f, 0.f, 0.f);
    for (int r = 0; r < nrep; ++r) {
        float4 v = *reinterpret_cast<const float4*>(esum_rep + (size_t)r * (K_CODE * E_DIM) + off);
        s4.x += v.x; s4.y += v.y; s4.z += v.z; s4.w += v.w;
    }
    float4 a = *reinterpret_cast<const float4*>(embed_avg + off);
    float4 nea, ne;
    nea.x = DECAYF * a.x + (1.0f - DECAYF) * s4.x;
    nea.y = DECAYF * a.y + (1.0f - DECAYF) * s4.y;
    nea.z = DECAYF * a.z + (1.0f - DECAYF) * s4.z;
    nea.w = DECAYF * a.w + (1.0f - DECAYF) * s4.w;
    ne.x = nea.x / cs; ne.y = nea.y / cs; ne.z = nea.z / cs; ne.w = nea.w / cs;
    *reinterpret_cast<float4*>(out_nea + off) = nea;
    *reinterpret_cast<float4*>(out_ne + off) = ne;
}

extern "C" void kernel_launch(void* const* d_in, const int* in_sizes, int n_in,
                              void* d_out, int out_size, void* d_ws, size_t ws_size,
                              hipStream_t stream) {
    const float* z_e = (const float*)d_in[0];
    const float* embed = (const float*)d_in[1];
    const float* cluster_size = (const float*)d_in[2];
    const float* embed_avg = (const float*)d_in[3];

    float* out = (float*)d_out;
    float* o_zq = out;                   // 4194304
    float* o_diff = out + 4194304;       // 1
    float* o_ind = out + 4194305;        // 65536
    float* o_ne = out + 4194305 + 65536; // 65536
    float* o_ncs = o_ne + 65536;         // 1024
    float* o_nea = o_ncs + 1024;         // 65536

    float* ws = (float*)d_ws;
    float* ws_wnorm = ws;                                        // [0,1024)
    float* ws_diff = ws + 1024;                                  // [1024]
    float* ws_n = ws + 1025;                                     // [1025]
    unsigned long long* ws_keys = (unsigned long long*)(ws + 2048);  // 65536 u64
    float* ws_onehot = ws + 2048 + 131072;                       // 133120
    float* ws_esum = ws + 2048 + 131072 + 8192;                  // 141312

    // choose replica count by available workspace
    int nrep = 1;
    while (nrep < 8 &&
           ws_size >= (size_t)(141312 + (size_t)(2 * nrep) * 65536) * sizeof(float))
        nrep *= 2;

    hipMemsetAsync(ws + 1024, 0, 2 * sizeof(float), stream);                       // diff, n
    hipMemsetAsync(ws_keys, 0xFF, (size_t)T_TOK * sizeof(unsigned long long), stream);  // keys = max
    hipMemsetAsync(ws_onehot, 0, (size_t)(8192 + (size_t)nrep * 65536) * sizeof(float),
                   stream);                                                        // onehot+esum

    wnorm_kernel<<<4, 256, 0, stream>>>(embed, ws_wnorm);
    argmin_kernel<<<1024, 512, 0, stream>>>(z_e, embed, ws_wnorm, ws_keys);
    combine_kernel<<<1024, 256, 0, stream>>>(z_e, embed, ws_keys, o_zq, o_ind, ws_diff,
                                             ws_esum, ws_onehot, nrep - 1);
    finalize_cs_kernel<<<1, 1024, 0, stream>>>(cluster_size, ws_onehot, ws_diff,
                                               o_diff, o_ncs, ws_n, nrep);
    finalize_embed_kernel<<<64, 256, 0, stream>>>(embed_avg, ws_esum, o_ncs, ws_n,
                                                  o_ne, o_nea, nrep);
}

// Round 2
// 199.859 us; speedup vs baseline: 1.3885x; 1.3885x over previous
//
#include <hip/hip_runtime.h>
#include <math.h>

#define T_TOK 65536
#define K_CODE 1024
#define E_DIM 64
#define DECAYF 0.99f
#define EPSF 1e-5f

// ---- dist_kernel geometry ----
#define TT 128            // tokens per block
#define DWAVES 4          // waves per block (wave owns 32 token rows)
#define CHUNK 256         // codes per LDS W chunk
#define NCH 4             // chunks covering K_CODE
#define QCAP 2048         // candidate queue capacity (expected ~250)
#define MARGIN 2.5e-3f    // >= 2x rigorous |approx-exact| bound (7.9e-4)

typedef short short8 __attribute__((ext_vector_type(8)));
typedef float f32x16 __attribute__((ext_vector_type(16)));

// --- exact-rounding helpers: block ffp-contract=fast fusion ---
__device__ __forceinline__ float mul_nf(float a, float b) {
#pragma clang fp contract(off)
    return a * b;
}
__device__ __forceinline__ float add_nf(float a, float b) {
#pragma clang fp contract(off)
    return a + b;
}
__device__ __forceinline__ float sub_nf(float a, float b) {
#pragma clang fp contract(off)
    return a - b;
}

// numpy pairwise_sum for n=64 of elementwise squares (array form)
__device__ __forceinline__ float np_sq_sum64(const float* v) {
    float r[8];
#pragma unroll
    for (int j = 0; j < 8; ++j) r[j] = mul_nf(v[j], v[j]);
#pragma unroll
    for (int i = 8; i < 64; i += 8) {
#pragma unroll
        for (int j = 0; j < 8; ++j) r[j] = add_nf(r[j], mul_nf(v[i + j], v[i + j]));
    }
    float s01 = add_nf(r[0], r[1]);
    float s23 = add_nf(r[2], r[3]);
    float s45 = add_nf(r[4], r[5]);
    float s67 = add_nf(r[6], r[7]);
    return add_nf(add_nf(s01, s23), add_nf(s45, s67));
}

// same pairwise ||x||^2 from a global row pointer (float4 loads)
__device__ __forceinline__ float np_sq_row(const float* xrow) {
    const float4* xp = reinterpret_cast<const float4*>(xrow);
    float r[8];
#pragma unroll
    for (int g = 0; g < 8; ++g) {
        float4 va = xp[2 * g], vb = xp[2 * g + 1];
        float e[8] = {va.x, va.y, va.z, va.w, vb.x, vb.y, vb.z, vb.w};
#pragma unroll
        for (int j = 0; j < 8; ++j) {
            if (g == 0) r[j] = mul_nf(e[j], e[j]);
            else        r[j] = add_nf(r[j], mul_nf(e[j], e[j]));
        }
    }
    float s01 = add_nf(r[0], r[1]);
    float s23 = add_nf(r[2], r[3]);
    float s45 = add_nf(r[4], r[5]);
    float s67 = add_nf(r[6], r[7]);
    return add_nf(add_nf(s01, s23), add_nf(s45, s67));
}

__device__ __forceinline__ unsigned short f2bf_rne(float f) {
    unsigned u = __float_as_uint(f);
    u += 0x7FFFu + ((u >> 16) & 1u);
    return (unsigned short)(u >> 16);
}

// ws layout (floats):
// [0, 1024)                    wnorm
// [1024]                       diff accumulator
// [1025]                       n (sum of new_cluster_size)
// [2048, 133120)               keys: u64[65536] (written fully by dist_kernel)
// [133120, 141312)             onehot replicas (8*1024)
// [141312, 174080)             w16: bf16[1024][64] as ushort (128 KB)
// [174080, +nrep*65536)        embed_sum replicas

__global__ __launch_bounds__(256) void wnorm_kernel(const float* __restrict__ embed,
                                                    float* __restrict__ wnorm,
                                                    unsigned short* __restrict__ w16) {
    int k = blockIdx.x * 256 + threadIdx.x;
    if (k < K_CODE) {
        float w[64];
        const float4* wp = reinterpret_cast<const float4*>(embed + (size_t)k * E_DIM);
#pragma unroll
        for (int i = 0; i < 16; ++i) {
            float4 v = wp[i];
            w[4 * i + 0] = v.x; w[4 * i + 1] = v.y; w[4 * i + 2] = v.z; w[4 * i + 3] = v.w;
        }
        wnorm[k] = np_sq_sum64(w);
        // bf16 RNE copy of the codebook row
        unsigned short* wr = w16 + (size_t)k * E_DIM;
#pragma unroll
        for (int i = 0; i < 64; ++i) wr[i] = f2bf_rne(w[i]);
    }
}

// exact fp32 recheck: bit-identical arithmetic to the verified argmin chain
// (ascending i single-accumulator FMA, dist = fl(fl(xn - fl(d+d)) + wn)),
// first-min semantics via u64 (monotone_dist<<32 | code) atomicMin.
__device__ __forceinline__ void exact_key(int t0, int tl, int code,
                                          const float* __restrict__ z_e,
                                          const float* __restrict__ embed,
                                          const float* xn_s, const float* wn_s,
                                          unsigned long long* key_s) {
    const float4* xp = reinterpret_cast<const float4*>(z_e + (size_t)(t0 + tl) * E_DIM);
    const float4* wp = reinterpret_cast<const float4*>(embed + (size_t)code * E_DIM);
    float d = 0.f;
#pragma unroll
    for (int m = 0; m < 16; ++m) {
        float4 x4 = xp[m];
        float4 w4 = wp[m];
        d = __builtin_fmaf(x4.x, w4.x, d);
        d = __builtin_fmaf(x4.y, w4.y, d);
        d = __builtin_fmaf(x4.z, w4.z, d);
        d = __builtin_fmaf(x4.w, w4.w, d);
    }
    float dist = add_nf(sub_nf(xn_s[tl], d + d), wn_s[code]);
    unsigned b = __float_as_uint(dist);
    unsigned mk = (b & 0x80000000u) ? ~b : (b | 0x80000000u);
    atomicMin(key_s + tl, ((unsigned long long)mk << 32) | (unsigned)code);
}

// MFMA approx-filter + exact-recheck argmin.
// Block = 256 thr = 4 waves; 128 tokens/block; each wave owns 32 token rows
// (a-frags for the whole 32x64 A panel live in 16 VGPRs/lane, loaded once).
// W (bf16) staged in LDS in 256-code chunks, double-buffered via reg-staged
// prefetch; rows XOR-slot-swizzled so b-frag ds_read_b128 is ~conflict-free.
// Pass 1 (chunks 0-3): per-token approx min (value only, registers).
// Pass 2 (chunks 4-7 = same codes): enqueue all (tok,code) with
// dist_approx <= min_approx + MARGIN; drain queue with the exact fp32 chain.
__global__ __launch_bounds__(256) void dist_kernel(const float* __restrict__ z_e,
                                                   const float* __restrict__ embed,
                                                   const float* __restrict__ wnorm,
                                                   const unsigned short* __restrict__ w16,
                                                   unsigned long long* __restrict__ keys_g) {
    __shared__ unsigned short Wb[2][CHUNK * E_DIM];  // 2 x 32 KB, swizzled slots
    __shared__ float wn_s[K_CODE];                   // 4 KB
    __shared__ float xn_s[TT];                       // 512 B
    __shared__ unsigned long long key_s[TT];         // 1 KB
    __shared__ unsigned q_s[QCAP];                   // 8 KB
    __shared__ int qc_s;

    int tid = threadIdx.x;
    int lane = tid & 63;
    int wave = tid >> 6;
    int g = lane >> 5;           // k-group within MFMA operand
    int t0 = blockIdx.x * TT;

    if (tid < TT) key_s[tid] = ~0ull;
    if (tid == 0) qc_s = 0;
    // wnorm -> LDS (1024 floats, 4/thread)
    *reinterpret_cast<float4*>(&wn_s[tid * 4]) =
        *reinterpret_cast<const float4*>(&wnorm[tid * 4]);
    // ||x||^2 per token (exact numpy pairwise), threads 0..127
    if (tid < TT) xn_s[tid] = np_sq_row(z_e + (size_t)(t0 + tid) * E_DIM);

    // a-frags: lane supplies A[m = lane&31][k = 16*kc + 8*g + j], bf16.
    int arow = wave * 32 + (lane & 31);
    const float* xrow = z_e + (size_t)(t0 + arow) * E_DIM;
    short8 afr[4];
#pragma unroll
    for (int kc = 0; kc < 4; ++kc) {
        int base = kc * 16 + g * 8;
        float4 a = *reinterpret_cast<const float4*>(xrow + base);
        float4 b = *reinterpret_cast<const float4*>(xrow + base + 4);
        afr[kc][0] = (short)f2bf_rne(a.x);
        afr[kc][1] = (short)f2bf_rne(a.y);
        afr[kc][2] = (short)f2bf_rne(a.z);
        afr[kc][3] = (short)f2bf_rne(a.w);
        afr[kc][4] = (short)f2bf_rne(b.x);
        afr[kc][5] = (short)f2bf_rne(b.y);
        afr[kc][6] = (short)f2bf_rne(b.z);
        afr[kc][7] = (short)f2bf_rne(b.w);
    }

    const uint4* w16q = reinterpret_cast<const uint4*>(w16);

    // prologue: stage chunk 0 into Wb[0] (swizzled: row cl, phys slot ps holds
    // global slot ps ^ (cl&7))
    {
        uint4 st[8];
#pragma unroll
        for (int it = 0; it < 8; ++it) {
            int idx = it * 256 + tid;
            int cl = idx >> 3, ps = idx & 7;
            int ls = ps ^ (cl & 7);
            st[it] = w16q[(size_t)cl * 8 + ls];
        }
#pragma unroll
        for (int it = 0; it < 8; ++it)
            reinterpret_cast<uint4*>(Wb[0])[it * 256 + tid] = st[it];
    }
    __syncthreads();  // Wb[0], wn_s, xn_s, key_s ready

    // per-lane xn for the 16 C rows (token rows fixed for the whole kernel)
    float xnr[16];
#pragma unroll
    for (int r = 0; r < 16; ++r) {
        int row = (r & 3) + 8 * (r >> 2) + 4 * g;
        xnr[r] = xn_s[wave * 32 + row];
    }
    float minr[16];
#pragma unroll
    for (int r = 0; r < 16; ++r) minr[r] = INFINITY;

    for (int ph = 0; ph < 2 * NCH; ++ph) {
        int cur = ph & 1;
        int cbase = (ph & 3) * CHUNK;
        uint4 st[8];
        if (ph < 2 * NCH - 1) {  // prefetch chunk (ph+1)&3 into regs
            int ncb = ((ph + 1) & 3) * CHUNK;
#pragma unroll
            for (int it = 0; it < 8; ++it) {
                int idx = it * 256 + tid;
                int cl = idx >> 3, ps = idx & 7;
                int ls = ps ^ (cl & 7);
                st[it] = w16q[(size_t)(ncb + cl) * 8 + ls];
            }
        }
        int pass = ph >> 2;
        // 8 code-tiles of 32 codes
        for (int tile = 0; tile < 8; ++tile) {
            int cloc = tile * 32 + (lane & 31);   // chunk-local code (this lane's column)
            float wn_c = wn_s[cbase + cloc];
            f32x16 acc;
#pragma unroll
            for (int i = 0; i < 16; ++i) acc[i] = 0.f;
#pragma unroll
            for (int kc = 0; kc < 4; ++kc) {
                int ps = (2 * kc + g) ^ (cloc & 7);
                short8 bfr = *reinterpret_cast<const short8*>(
                    &Wb[cur][cloc * E_DIM + ps * 8]);
                acc = __builtin_amdgcn_mfma_f32_32x32x16_bf16(afr[kc], bfr, acc, 0, 0, 0);
            }
            if (pass == 0) {
#pragma unroll
                for (int r = 0; r < 16; ++r) {
                    float dist = __builtin_fmaf(acc[r], -2.0f, xnr[r] + wn_c);
                    minr[r] = fminf(minr[r], dist);
                }
            } else {
                float tmin = INFINITY;
#pragma unroll
                for (int r = 0; r < 16; ++r) {
                    float dist = __builtin_fmaf(acc[r], -2.0f, xnr[r] + wn_c);
                    tmin = fminf(tmin, dist - minr[r]);
                }
                if (tmin <= MARGIN) {  // rare (~2% of lane-tiles)
#pragma unroll
                    for (int r = 0; r < 16; ++r) {
                        float dist = __builtin_fmaf(acc[r], -2.0f, xnr[r] + wn_c);
                        if (dist <= minr[r] + MARGIN) {
                            int row = (r & 3) + 8 * (r >> 2) + 4 * g;
                            int tl = wave * 32 + row;
                            int code = cbase + cloc;
                            int slot = atomicAdd(&qc_s, 1);
                            if (slot < QCAP)
                                q_s[slot] = ((unsigned)tl << 10) | (unsigned)code;
                            else  // overflow fallback: exact inline (never in practice)
                                exact_key(t0, tl, code, z_e, embed, xn_s, wn_s, key_s);
                        }
                    }
                }
            }
        }
        if (ph == NCH - 1) {
            // finish pass-1 min: reduce across the 32 columns (xor masks < 32
            // never cross the lane>>5 row-group boundary)
#pragma unroll
            for (int off = 1; off < 32; off <<= 1) {
#pragma unroll
                for (int r = 0; r < 16; ++r)
                    minr[r] = fminf(minr[r], __shfl_xor(minr[r], off, 64));
            }
        }
        if (ph < 2 * NCH - 1) {  // write staged chunk into the other buffer
#pragma unroll
            for (int it = 0; it < 8; ++it)
                reinterpret_cast<uint4*>(Wb[cur ^ 1])[it * 256 + tid] = st[it];
        }
        __syncthreads();
    }

    // drain candidate queue with the exact fp32 chain
    int qn = qc_s;
    if (qn > QCAP) qn = QCAP;
    for (int e = tid; e < qn; e += 256) {
        unsigned q = q_s[e];
        int tl = (int)(q >> 10);
        int code = (int)(q & 1023u);
        exact_key(t0, tl, code, z_e, embed, xn_s, wn_s, key_s);
    }
    __syncthreads();
    if (tid < TT) keys_g[t0 + tid] = key_s[tid];
}

// Combine: gather winner, straight-through z_q + diff partial, fused EMA
// scatter (unchanged from the verified passing version).
__global__ __launch_bounds__(256) void combine_kernel(const float* __restrict__ z_e,
                                                      const float* __restrict__ embed,
                                                      const unsigned long long* __restrict__ keys,
                                                      float* __restrict__ out_zq,
                                                      float* __restrict__ out_ind,
                                                      float* __restrict__ diff_acc,
                                                      float* __restrict__ esum_rep,
                                                      float* __restrict__ onehot_rep,
                                                      int rep_mask) {
    __shared__ int sidx[64];
    __shared__ float sred[4];
    int tid = threadIdx.x;
    int t0 = blockIdx.x * 64;

    if (tid < 64) {
        unsigned long long kv = keys[t0 + tid];
        int bi = (int)(kv & 0x3FFull);
        sidx[tid] = bi;
        out_ind[t0 + tid] = (float)bi;
    }
    __syncthreads();

    float ds = 0.f;
#pragma unroll
    for (int u = 0; u < 4; ++u) {
        int v = u * 256 + tid;
        int tl = v >> 4;
        int c = v & 15;
        int bi = sidx[tl];
        float4 w4 = *reinterpret_cast<const float4*>(embed + (size_t)bi * E_DIM + c * 4);
        float4 x4 = *reinterpret_cast<const float4*>(z_e + (size_t)(t0 + tl) * E_DIM + c * 4);
        float rx = sub_nf(w4.x, x4.x);
        float ry = sub_nf(w4.y, x4.y);
        float rz = sub_nf(w4.z, x4.z);
        float rw = sub_nf(w4.w, x4.w);
        float4 o;
        o.x = add_nf(x4.x, rx);
        o.y = add_nf(x4.y, ry);
        o.z = add_nf(x4.z, rz);
        o.w = add_nf(x4.w, rw);
        *reinterpret_cast<float4*>(out_zq + (size_t)(t0 + tl) * E_DIM + c * 4) = o;
        ds = __builtin_fmaf(rx, rx, ds);
        ds = __builtin_fmaf(ry, ry, ds);
        ds = __builtin_fmaf(rz, rz, ds);
        ds = __builtin_fmaf(rw, rw, ds);
    }
#pragma unroll
    for (int o = 32; o > 0; o >>= 1) ds += __shfl_down(ds, o, 64);
    if ((tid & 63) == 0) sred[tid >> 6] = ds;
    __syncthreads();
    if (tid == 0) atomicAdd(diff_acc, sred[0] + sred[1] + sred[2] + sred[3]);

    int lane = tid & 63;
    int wv = tid >> 6;
    int rep = blockIdx.x & rep_mask;
    float* esum = esum_rep + (size_t)rep * (K_CODE * E_DIM);
    float* onehot = onehot_rep + (size_t)rep * K_CODE;
#pragma unroll
    for (int j = 0; j < 16; ++j) {
        int tl = wv * 16 + j;
        int bi = sidx[tl];
        float xv = z_e[(size_t)(t0 + tl) * E_DIM + lane];
        atomicAdd(&esum[(size_t)bi * E_DIM + lane], xv);
        if (lane == 0) atomicAdd(&onehot[bi], 1.0f);
    }
}

// ncs, n, diff: single block (tiny)
__global__ __launch_bounds__(1024) void finalize_cs_kernel(const float* __restrict__ cluster_size,
                                                           const float* __restrict__ onehot_rep,
                                                           const float* __restrict__ ws_diff,
                                                           float* __restrict__ out_diff,
                                                           float* __restrict__ out_ncs,
                                                           float* __restrict__ ws_n,
                                                           int nrep) {
    int k = threadIdx.x;
    float oh = 0.f;
    for (int r = 0; r < nrep; ++r) oh += onehot_rep[(size_t)r * K_CODE + k];
    float ncs = DECAYF * cluster_size[k] + (1.0f - DECAYF) * oh;
    out_ncs[k] = ncs;

    __shared__ float red[1024];
    red[k] = ncs;
    __syncthreads();
#pragma unroll
    for (int s = 512; s > 0; s >>= 1) {
        if (k < s) red[k] += red[k + s];
        __syncthreads();
    }
    if (k == 0) {
        ws_n[0] = red[0];
        out_diff[0] = ws_diff[0] * (1.0f / 4194304.0f);  // /2^22 exact
    }
}

// embed_avg / embed update spread across 64 blocks
__global__ __launch_bounds__(256) void finalize_embed_kernel(const float* __restrict__ embed_avg,
                                                             const float* __restrict__ esum_rep,
                                                             const float* __restrict__ out_ncs,
                                                             const float* __restrict__ ws_n,
                                                             float* __restrict__ out_ne,
                                                             float* __restrict__ out_nea,
                                                             int nrep) {
    int gid = blockIdx.x * 256 + threadIdx.x;
    int k = gid >> 4;        // row
    int c = gid & 15;        // float4 chunk
    float n = ws_n[0];
    float ncs = out_ncs[k];
    float cs = (ncs + EPSF) / (n + (float)K_CODE * EPSF) * n;

    size_t off = (size_t)k * E_DIM + (size_t)c * 4;
    float4 s4 = make_float4(0.f, 0.f, 0.f, 0.f);
    for (int r = 0; r < nrep; ++r) {
        float4 v = *reinterpret_cast<const float4*>(esum_rep + (size_t)r * (K_CODE * E_DIM) + off);
        s4.x += v.x; s4.y += v.y; s4.z += v.z; s4.w += v.w;
    }
    float4 a = *reinterpret_cast<const float4*>(embed_avg + off);
    float4 nea, ne;
    nea.x = DECAYF * a.x + (1.0f - DECAYF) * s4.x;
    nea.y = DECAYF * a.y + (1.0f - DECAYF) * s4.y;
    nea.z = DECAYF * a.z + (1.0f - DECAYF) * s4.z;
    nea.w = DECAYF * a.w + (1.0f - DECAYF) * s4.w;
    ne.x = nea.x / cs; ne.y = nea.y / cs; ne.z = nea.z / cs; ne.w = nea.w / cs;
    *reinterpret_cast<float4*>(out_nea + off) = nea;
    *reinterpret_cast<float4*>(out_ne + off) = ne;
}

extern "C" void kernel_launch(void* const* d_in, const int* in_sizes, int n_in,
                              void* d_out, int out_size, void* d_ws, size_t ws_size,
                              hipStream_t stream) {
    const float* z_e = (const float*)d_in[0];
    const float* embed = (const float*)d_in[1];
    const float* cluster_size = (const float*)d_in[2];
    const float* embed_avg = (const float*)d_in[3];

    float* out = (float*)d_out;
    float* o_zq = out;                   // 4194304
    float* o_diff = out + 4194304;       // 1
    float* o_ind = out + 4194305;        // 65536
    float* o_ne = out + 4194305 + 65536; // 65536
    float* o_ncs = o_ne + 65536;         // 1024
    float* o_nea = o_ncs + 1024;         // 65536

    float* ws = (float*)d_ws;
    float* ws_wnorm = ws;                                            // [0,1024)
    float* ws_diff = ws + 1024;                                      // [1024]
    float* ws_n = ws + 1025;                                         // [1025]
    unsigned long long* ws_keys = (unsigned long long*)(ws + 2048);  // u64[65536]
    float* ws_onehot = ws + 133120;                                  // 8*1024
    unsigned short* ws_w16 = (unsigned short*)(ws + 141312);         // bf16[1024][64]
    float* ws_esum = ws + 174080;                                    // nrep*65536

    int nrep = 1;
    while (nrep < 8 &&
           ws_size >= (size_t)(174080 + (size_t)(2 * nrep) * 65536) * sizeof(float))
        nrep *= 2;

    hipMemsetAsync(ws + 1024, 0, 2 * sizeof(float), stream);  // diff, n
    hipMemsetAsync(ws_onehot, 0, (size_t)(8192 + (size_t)nrep * 65536) * sizeof(float),
                   stream);  // onehot + esum

    wnorm_kernel<<<4, 256, 0, stream>>>(embed, ws_wnorm, ws_w16);
    dist_kernel<<<T_TOK / TT, 256, 0, stream>>>(z_e, embed, ws_wnorm, ws_w16, ws_keys);
    combine_kernel<<<1024, 256, 0, stream>>>(z_e, embed, ws_keys, o_zq, o_ind, ws_diff,
                                             ws_esum, ws_onehot, nrep - 1);
    finalize_cs_kernel<<<1, 1024, 0, stream>>>(cluster_size, ws_onehot, ws_diff,
                                               o_diff, o_ncs, ws_n, nrep);
    finalize_embed_kernel<<<64, 256, 0, stream>>>(embed_avg, ws_esum, o_ncs, ws_n,
                                                  o_ne, o_nea, nrep);
}

// Round 3
// 181.668 us; speedup vs baseline: 1.5275x; 1.1001x over previous
//
#include <hip/hip_runtime.h>
#include <math.h>

#define T_TOK 65536
#define K_CODE 1024
#define E_DIM 64
#define DECAYF 0.99f
#define EPSF 1e-5f

// ---- dist_kernel geometry ----
#define TT 256            // tokens per block (8 waves x 32 rows)
#define QCAP 2048         // candidate queue capacity (expected ~360)
#define MARGIN 2.5e-3f    // >= 2x rigorous |approx-exact| bound (~5.6e-4)

typedef short short8 __attribute__((ext_vector_type(8)));
typedef float f32x16 __attribute__((ext_vector_type(16)));

// --- exact-rounding helpers: block ffp-contract=fast fusion ---
__device__ __forceinline__ float mul_nf(float a, float b) {
#pragma clang fp contract(off)
    return a * b;
}
__device__ __forceinline__ float add_nf(float a, float b) {
#pragma clang fp contract(off)
    return a + b;
}
__device__ __forceinline__ float sub_nf(float a, float b) {
#pragma clang fp contract(off)
    return a - b;
}

// numpy pairwise_sum for n=64 of elementwise squares (array form)
__device__ __forceinline__ float np_sq_sum64(const float* v) {
    float r[8];
#pragma unroll
    for (int j = 0; j < 8; ++j) r[j] = mul_nf(v[j], v[j]);
#pragma unroll
    for (int i = 8; i < 64; i += 8) {
#pragma unroll
        for (int j = 0; j < 8; ++j) r[j] = add_nf(r[j], mul_nf(v[i + j], v[i + j]));
    }
    float s01 = add_nf(r[0], r[1]);
    float s23 = add_nf(r[2], r[3]);
    float s45 = add_nf(r[4], r[5]);
    float s67 = add_nf(r[6], r[7]);
    return add_nf(add_nf(s01, s23), add_nf(s45, s67));
}

// same pairwise ||x||^2 from a global row pointer (float4 loads)
__device__ __forceinline__ float np_sq_row(const float* xrow) {
    const float4* xp = reinterpret_cast<const float4*>(xrow);
    float r[8];
#pragma unroll
    for (int g = 0; g < 8; ++g) {
        float4 va = xp[2 * g], vb = xp[2 * g + 1];
        float e[8] = {va.x, va.y, va.z, va.w, vb.x, vb.y, vb.z, vb.w};
#pragma unroll
        for (int j = 0; j < 8; ++j) {
            if (g == 0) r[j] = mul_nf(e[j], e[j]);
            else        r[j] = add_nf(r[j], mul_nf(e[j], e[j]));
        }
    }
    float s01 = add_nf(r[0], r[1]);
    float s23 = add_nf(r[2], r[3]);
    float s45 = add_nf(r[4], r[5]);
    float s67 = add_nf(r[6], r[7]);
    return add_nf(add_nf(s01, s23), add_nf(s45, s67));
}

__device__ __forceinline__ unsigned f2bf_rne(float f) {
    unsigned u = __float_as_uint(f);
    u += 0x7FFFu + ((u >> 16) & 1u);
    return (u >> 16);
}

// ws layout (floats):
// [0, 1024)            wnorm
// [1024, 33792)        w16: bf16[1024][64] as ushort (128 KB)
// [33792]              diff accumulator
// [33793]              n (sum of new_cluster_size)
// [33794, 33796)       pad
// [33796, 41988)       onehot replicas (8*1024)
// [41988, +nrep*65536) embed_sum replicas
// single contiguous memset: [33792, 41988 + nrep*65536)

__global__ __launch_bounds__(256) void wnorm_kernel(const float* __restrict__ embed,
                                                    float* __restrict__ wnorm,
                                                    unsigned short* __restrict__ w16) {
    int k = blockIdx.x * 256 + threadIdx.x;
    if (k < K_CODE) {
        float w[64];
        const float4* wp = reinterpret_cast<const float4*>(embed + (size_t)k * E_DIM);
#pragma unroll
        for (int i = 0; i < 16; ++i) {
            float4 v = wp[i];
            w[4 * i + 0] = v.x; w[4 * i + 1] = v.y; w[4 * i + 2] = v.z; w[4 * i + 3] = v.w;
        }
        wnorm[k] = np_sq_sum64(w);
        // bf16 RNE copy of the codebook row, packed + vectorized stores
        unsigned uu[32];
#pragma unroll
        for (int i = 0; i < 32; ++i)
            uu[i] = f2bf_rne(w[2 * i]) | (f2bf_rne(w[2 * i + 1]) << 16);
        uint4* wq = reinterpret_cast<uint4*>(w16 + (size_t)k * E_DIM);
#pragma unroll
        for (int q = 0; q < 8; ++q)
            wq[q] = make_uint4(uu[4 * q], uu[4 * q + 1], uu[4 * q + 2], uu[4 * q + 3]);
    }
}

// exact fp32 recheck: bit-identical arithmetic to the verified argmin chain
// (ascending i single-accumulator FMA, dist = fl(fl(xn - fl(d+d)) + wn)),
// first-min semantics via u64 (monotone_dist<<32 | code) atomicMin on LDS.
__device__ __forceinline__ void exact_key(int t0, int tl, int code,
                                          const float* __restrict__ z_e,
                                          const float* __restrict__ embed,
                                          const float* xn_s, const float* wn_s,
                                          unsigned long long* key_s) {
    const float4* xp = reinterpret_cast<const float4*>(z_e + (size_t)(t0 + tl) * E_DIM);
    const float4* wp = reinterpret_cast<const float4*>(embed + (size_t)code * E_DIM);
    float d = 0.f;
#pragma unroll
    for (int m = 0; m < 16; ++m) {
        float4 x4 = xp[m];
        float4 w4 = wp[m];
        d = __builtin_fmaf(x4.x, w4.x, d);
        d = __builtin_fmaf(x4.y, w4.y, d);
        d = __builtin_fmaf(x4.z, w4.z, d);
        d = __builtin_fmaf(x4.w, w4.w, d);
    }
    float dist = add_nf(sub_nf(xn_s[tl], d + d), wn_s[code]);
    unsigned b = __float_as_uint(dist);
    unsigned mk = (b & 0x80000000u) ? ~b : (b | 0x80000000u);
    atomicMin(key_s + tl, ((unsigned long long)mk << 32) | (unsigned)code);
}

// MFMA approx-filter + exact-recheck argmin, fully fused (z_q / diff / EMA
// scatter included). Block = 512 thr = 8 waves; 256 tokens/block; 256 blocks
// = 1 block/CU. The WHOLE bf16 codebook (128 KB) is staged into LDS ONCE
// (XOR-slot swizzle, verified round 2); the two dist passes then run with
// ZERO barriers and ZERO global traffic:
//   pass 1: 32 tiles of {4 ds_read_b128, 4 MFMA, min-track}
//   cross-column shfl reduce -> per-token global approx min
//   pass 2: same tiles; enqueue (tok,code) with dist <= min + MARGIN
//   drain queue with the exact fp32 chain -> key_s
//   fused epilogue: z_q + straight-through + diff partial + esum/onehot
//   scatter (winner row is wave-uniform -> coalesced gathers/atomics)
__global__ __launch_bounds__(512) void dist_kernel(const float* __restrict__ z_e,
                                                   const float* __restrict__ embed,
                                                   const float* __restrict__ wnorm,
                                                   const unsigned short* __restrict__ w16,
                                                   float* __restrict__ out_zq,
                                                   float* __restrict__ out_ind,
                                                   float* __restrict__ diff_acc,
                                                   float* __restrict__ esum_rep,
                                                   float* __restrict__ onehot_rep,
                                                   int rep_mask) {
    __shared__ unsigned short Ws[K_CODE * E_DIM];  // 128 KB, swizzled slots
    __shared__ float wn_s[K_CODE];                 // 4 KB
    __shared__ float xn_s[TT];                     // 1 KB
    __shared__ unsigned long long key_s[TT];       // 2 KB
    __shared__ unsigned q_s[QCAP];                 // 8 KB
    __shared__ int qc_s;

    int tid = threadIdx.x;
    int lane = tid & 63;
    int wave = tid >> 6;
    int g = lane >> 5;  // k-group within MFMA operand
    int t0 = blockIdx.x * TT;

    if (tid < TT) key_s[tid] = ~0ull;
    if (tid == 0) qc_s = 0;
    // wnorm -> LDS (1024 floats, 2/thread)
    *reinterpret_cast<float2*>(&wn_s[tid * 2]) =
        *reinterpret_cast<const float2*>(&wnorm[tid * 2]);
    // ||x||^2 per token (exact numpy pairwise), threads 0..255
    if (tid < TT) xn_s[tid] = np_sq_row(z_e + (size_t)(t0 + tid) * E_DIM);

    // stage FULL codebook once: 8192 uint4 over 512 threads = 16 each.
    // phys slot ps of row cl holds logical slot ps ^ (cl&7).
    {
        const uint4* wq = reinterpret_cast<const uint4*>(w16);
        uint4* WsQ = reinterpret_cast<uint4*>(Ws);
#pragma unroll
        for (int it = 0; it < 16; ++it) {
            int idx = it * 512 + tid;
            int cl = idx >> 3, ps = idx & 7;
            WsQ[cl * 8 + ps] = wq[(size_t)cl * 8 + (ps ^ (cl & 7))];
        }
    }

    // a-frags: lane supplies A[m = lane&31][k = 16*kc + 8*g + j], bf16.
    int arow = wave * 32 + (lane & 31);
    const float* xrow = z_e + (size_t)(t0 + arow) * E_DIM;
    short8 afr[4];
#pragma unroll
    for (int kc = 0; kc < 4; ++kc) {
        int base = kc * 16 + g * 8;
        float4 a = *reinterpret_cast<const float4*>(xrow + base);
        float4 b = *reinterpret_cast<const float4*>(xrow + base + 4);
        afr[kc][0] = (short)f2bf_rne(a.x);
        afr[kc][1] = (short)f2bf_rne(a.y);
        afr[kc][2] = (short)f2bf_rne(a.z);
        afr[kc][3] = (short)f2bf_rne(a.w);
        afr[kc][4] = (short)f2bf_rne(b.x);
        afr[kc][5] = (short)f2bf_rne(b.y);
        afr[kc][6] = (short)f2bf_rne(b.z);
        afr[kc][7] = (short)f2bf_rne(b.w);
    }

    __syncthreads();  // Ws, wn_s, xn_s, key_s ready — the ONLY pre-drain barrier

    // per-lane xn for the 16 C rows
    float xnr[16];
#pragma unroll
    for (int r = 0; r < 16; ++r) {
        int row = (r & 3) + 8 * (r >> 2) + 4 * g;
        xnr[r] = xn_s[wave * 32 + row];
    }
    float minr[16];
#pragma unroll
    for (int r = 0; r < 16; ++r) minr[r] = INFINITY;

    // ---- pass 1: track per-(lane,row) approx min ----
#pragma unroll 2
    for (int tile = 0; tile < 32; ++tile) {
        int code = tile * 32 + (lane & 31);
        float wn_c = wn_s[code];
        f32x16 acc;
#pragma unroll
        for (int i = 0; i < 16; ++i) acc[i] = 0.f;
#pragma unroll
        for (int kc = 0; kc < 4; ++kc) {
            int ps = (2 * kc + g) ^ (code & 7);
            short8 bfr = *reinterpret_cast<const short8*>(&Ws[code * E_DIM + ps * 8]);
            acc = __builtin_amdgcn_mfma_f32_32x32x16_bf16(afr[kc], bfr, acc, 0, 0, 0);
        }
#pragma unroll
        for (int r = 0; r < 16; ++r) {
            float dist = __builtin_fmaf(acc[r], -2.0f, xnr[r] + wn_c);
            minr[r] = fminf(minr[r], dist);
        }
    }

    // cross-column reduce (xor masks < 32 stay inside the lane>>5 group)
#pragma unroll
    for (int off = 1; off < 32; off <<= 1) {
#pragma unroll
        for (int r = 0; r < 16; ++r)
            minr[r] = fminf(minr[r], __shfl_xor(minr[r], off, 64));
    }

    // ---- pass 2: enqueue margin candidates (LDS still resident) ----
#pragma unroll 2
    for (int tile = 0; tile < 32; ++tile) {
        int code = tile * 32 + (lane & 31);
        float wn_c = wn_s[code];
        f32x16 acc;
#pragma unroll
        for (int i = 0; i < 16; ++i) acc[i] = 0.f;
#pragma unroll
        for (int kc = 0; kc < 4; ++kc) {
            int ps = (2 * kc + g) ^ (code & 7);
            short8 bfr = *reinterpret_cast<const short8*>(&Ws[code * E_DIM + ps * 8]);
            acc = __builtin_amdgcn_mfma_f32_32x32x16_bf16(afr[kc], bfr, acc, 0, 0, 0);
        }
        float tmin = INFINITY;
#pragma unroll
        for (int r = 0; r < 16; ++r) {
            float dist = __builtin_fmaf(acc[r], -2.0f, xnr[r] + wn_c);
            tmin = fminf(tmin, dist - minr[r]);
        }
        if (tmin <= MARGIN) {  // rare
#pragma unroll
            for (int r = 0; r < 16; ++r) {
                float dist = __builtin_fmaf(acc[r], -2.0f, xnr[r] + wn_c);
                if (dist <= minr[r] + MARGIN) {
                    int row = (r & 3) + 8 * (r >> 2) + 4 * g;
                    int tl = wave * 32 + row;
                    int slot = atomicAdd(&qc_s, 1);
                    if (slot < QCAP)
                        q_s[slot] = ((unsigned)tl << 10) | (unsigned)code;
                    else  // overflow fallback: exact inline (never in practice)
                        exact_key(t0, tl, code, z_e, embed, xn_s, wn_s, key_s);
                }
            }
        }
    }
    __syncthreads();

    // drain candidate queue with the exact fp32 chain
    int qn = qc_s;
    if (qn > QCAP) qn = QCAP;
    for (int e = tid; e < qn; e += 512) {
        unsigned q = q_s[e];
        int tl = (int)(q >> 10);
        int code = (int)(q & 1023u);
        exact_key(t0, tl, code, z_e, embed, xn_s, wn_s, key_s);
    }
    __syncthreads();

    // ---- fused epilogue: ind, z_q, diff, EMA scatter ----
    if (tid < TT) out_ind[t0 + tid] = (float)(unsigned)(key_s[tid] & 1023ull);

    int rep = blockIdx.x & rep_mask;
    float* esum = esum_rep + (size_t)rep * (K_CODE * E_DIM);
    float* onehot = onehot_rep + (size_t)rep * K_CODE;

    float ds = 0.f;
#pragma unroll 4
    for (int it = 0; it < 32; ++it) {
        int tl = wave * 32 + it;                     // wave-uniform
        int bi = (int)(unsigned)(key_s[tl] & 1023ull);  // wave-uniform broadcast
        float xv = z_e[(size_t)(t0 + tl) * E_DIM + lane];   // coalesced 256B row
        float wv = embed[(size_t)bi * E_DIM + lane];        // coalesced 256B row
        float rr = sub_nf(wv, xv);                   // np: r = fl(w - x)
        out_zq[(size_t)(t0 + tl) * E_DIM + lane] = add_nf(xv, rr);  // fl(x + r)
        ds = __builtin_fmaf(rr, rr, ds);
        atomicAdd(&esum[(size_t)bi * E_DIM + lane], xv);
        if (lane == 0) atomicAdd(&onehot[bi], 1.0f);
    }
#pragma unroll
    for (int o = 32; o > 0; o >>= 1) ds += __shfl_down(ds, o, 64);
    if (lane == 0) atomicAdd(diff_acc, ds);
}

// ncs, n, diff: single block (tiny)
__global__ __launch_bounds__(1024) void finalize_cs_kernel(const float* __restrict__ cluster_size,
                                                           const float* __restrict__ onehot_rep,
                                                           const float* __restrict__ ws_diff,
                                                           float* __restrict__ out_diff,
                                                           float* __restrict__ out_ncs,
                                                           float* __restrict__ ws_n,
                                                           int nrep) {
    int k = threadIdx.x;
    float oh = 0.f;
    for (int r = 0; r < nrep; ++r) oh += onehot_rep[(size_t)r * K_CODE + k];
    float ncs = DECAYF * cluster_size[k] + (1.0f - DECAYF) * oh;
    out_ncs[k] = ncs;

    __shared__ float red[1024];
    red[k] = ncs;
    __syncthreads();
#pragma unroll
    for (int s = 512; s > 0; s >>= 1) {
        if (k < s) red[k] += red[k + s];
        __syncthreads();
    }
    if (k == 0) {
        ws_n[0] = red[0];
        out_diff[0] = ws_diff[0] * (1.0f / 4194304.0f);  // /2^22 exact
    }
}

// embed_avg / embed update spread across 64 blocks
__global__ __launch_bounds__(256) void finalize_embed_kernel(const float* __restrict__ embed_avg,
                                                             const float* __restrict__ esum_rep,
                                                             const float* __restrict__ out_ncs,
                                                             const float* __restrict__ ws_n,
                                                             float* __restrict__ out_ne,
                                                             float* __restrict__ out_nea,
                                                             int nrep) {
    int gid = blockIdx.x * 256 + threadIdx.x;
    int k = gid >> 4;        // row
    int c = gid & 15;        // float4 chunk
    float n = ws_n[0];
    float ncs = out_ncs[k];
    float cs = (ncs + EPSF) / (n + (float)K_CODE * EPSF) * n;

    size_t off = (size_t)k * E_DIM + (size_t)c * 4;
    float4 s4 = make_float4(0.f, 0.f, 0.f, 0.f);
    for (int r = 0; r < nrep; ++r) {
        float4 v = *reinterpret_cast<const float4*>(esum_rep + (size_t)r * (K_CODE * E_DIM) + off);
        s4.x += v.x; s4.y += v.y; s4.z += v.z; s4.w += v.w;
    }
    float4 a = *reinterpret_cast<const float4*>(embed_avg + off);
    float4 nea, ne;
    nea.x = DECAYF * a.x + (1.0f - DECAYF) * s4.x;
    nea.y = DECAYF * a.y + (1.0f - DECAYF) * s4.y;
    nea.z = DECAYF * a.z + (1.0f - DECAYF) * s4.z;
    nea.w = DECAYF * a.w + (1.0f - DECAYF) * s4.w;
    ne.x = nea.x / cs; ne.y = nea.y / cs; ne.z = nea.z / cs; ne.w = nea.w / cs;
    *reinterpret_cast<float4*>(out_nea + off) = nea;
    *reinterpret_cast<float4*>(out_ne + off) = ne;
}

extern "C" void kernel_launch(void* const* d_in, const int* in_sizes, int n_in,
                              void* d_out, int out_size, void* d_ws, size_t ws_size,
                              hipStream_t stream) {
    const float* z_e = (const float*)d_in[0];
    const float* embed = (const float*)d_in[1];
    const float* cluster_size = (const float*)d_in[2];
    const float* embed_avg = (const float*)d_in[3];

    float* out = (float*)d_out;
    float* o_zq = out;                   // 4194304
    float* o_diff = out + 4194304;       // 1
    float* o_ind = out + 4194305;        // 65536
    float* o_ne = out + 4194305 + 65536; // 65536
    float* o_ncs = o_ne + 65536;         // 1024
    float* o_nea = o_ncs + 1024;         // 65536

    float* ws = (float*)d_ws;
    float* ws_wnorm = ws;                                   // [0,1024)
    unsigned short* ws_w16 = (unsigned short*)(ws + 1024);  // 32768 floats worth
    float* ws_diff = ws + 33792;
    float* ws_n = ws + 33793;
    float* ws_onehot = ws + 33796;                          // 8*1024
    float* ws_esum = ws + 41988;                            // nrep*65536

    int nrep = 1;
    while (nrep < 8 &&
           (size_t)(41988 + (size_t)(2 * nrep) * 65536) * sizeof(float) <= ws_size)
        nrep *= 2;

    // one contiguous clear: diff, n, pad, onehot, esum
    hipMemsetAsync(ws + 33792, 0,
                   (size_t)(4 + 8192 + (size_t)nrep * 65536) * sizeof(float), stream);

    wnorm_kernel<<<4, 256, 0, stream>>>(embed, ws_wnorm, ws_w16);
    dist_kernel<<<T_TOK / TT, 512, 0, stream>>>(z_e, embed, ws_wnorm, ws_w16,
                                                o_zq, o_ind, ws_diff,
                                                ws_esum, ws_onehot, nrep - 1);
    finalize_cs_kernel<<<1, 1024, 0, stream>>>(cluster_size, ws_onehot, ws_diff,
                                               o_diff, o_ncs, ws_n, nrep);
    finalize_embed_kernel<<<64, 256, 0, stream>>>(embed_avg, ws_esum, o_ncs, ws_n,
                                                  o_ne, o_nea, nrep);
}